// Round 4
// baseline (259.958 us; speedup 1.0000x reference)
//
#include <hip/hip_runtime.h>

// FinDiffNonUniform: out[n,b] = sum_{s<7} coef[n,s] * y[n + off[n,s], b]
// N=8192, B=4096, S=7, fp32.
//
// Round-5 (resubmit after infra failure): buy in-flight bytes with TLP, not
// ILP. Rounds 0/2 proved the allocator resolves register pressure above its
// 64-reg (8-wave) target by re-serializing loads (VGPR_Count=36 both times)
// -- C-level barriers can't stop that. So keep per-thread state UNDER the
// target: R=1, 7 row loads + 1 acc ~= 44 VGPRs -> nothing to squeeze, loads
// stay live. Parallelism does the latency hiding: 32768 blocks (128/CU, full
// 32-wave occupancy); even fully serialized waves keep ~32 KB/CU in flight
// vs the ~22 KB the BW-latency product needs. L1 absorbs the 7x vertical
// gather (28 KB/block working set < 32 KB L1); bijective XCD swizzle gives
// same-XCD blocks consecutive n -> 6/7-row L2 reuse. Nontemporal stores keep
// the write stream out of the caches.

#define FD_N   8192
#define FD_B   4096
#define FD_S   7
#define HALO   3
#define NCHUNK 4                     // 1024-float column chunks
#define NWG    (FD_N * NCHUNK)       // 32768 blocks (divisible by 8)
#define NXCD   8

typedef float v4f __attribute__((ext_vector_type(4)));

__global__ __launch_bounds__(256) void
_FinDiffNonUniform_51608327029442_kernel(const float* __restrict__ y,
                                         const float* __restrict__ coef,
                                         const int*   __restrict__ offs,
                                         float*       __restrict__ out) {
    // Bijective XCD swizzle (NWG % 8 == 0): each XCD receives a contiguous
    // run of logical ids -> consecutive n within one column chunk, so
    // co-resident blocks on an XCD share 6/7 stencil rows in its L2.
    const int bid   = blockIdx.x;
    const int id    = (bid & (NXCD - 1)) * (NWG / NXCD) + (bid >> 3);
    const int n     = id & (FD_N - 1);
    const int chunk = id >> 13;                    // id / FD_N
    const int b     = (chunk << 10) + (threadIdx.x << 2);

    const float* __restrict__ c = coef + (size_t)n * FD_S;   // block-uniform

    if (n >= HALO && n < FD_N - HALO) {
        // ---- interior: centered [-3..3] stencil, 7 independent loads ----
        const float* ybase = y + (size_t)(n - HALO) * FD_B + b;

        v4f w0 = *reinterpret_cast<const v4f*>(ybase + 0 * (size_t)FD_B);
        v4f w1 = *reinterpret_cast<const v4f*>(ybase + 1 * (size_t)FD_B);
        v4f w2 = *reinterpret_cast<const v4f*>(ybase + 2 * (size_t)FD_B);
        v4f w3 = *reinterpret_cast<const v4f*>(ybase + 3 * (size_t)FD_B);
        v4f w4 = *reinterpret_cast<const v4f*>(ybase + 4 * (size_t)FD_B);
        v4f w5 = *reinterpret_cast<const v4f*>(ybase + 5 * (size_t)FD_B);
        v4f w6 = *reinterpret_cast<const v4f*>(ybase + 6 * (size_t)FD_B);
        // Loads may not sink below this point.
        asm volatile("" ::: "memory");

        // Consume in arrival order -> natural vmcnt(6..0) decay.
        v4f acc = c[0] * w0;
        acc += c[1] * w1;
        acc += c[2] * w2;
        acc += c[3] * w3;
        acc += c[4] * w4;
        acc += c[5] * w5;
        acc += c[6] * w6;

        __builtin_nontemporal_store(
            acc, reinterpret_cast<v4f*>(out + (size_t)n * FD_B + b));
    } else {
        // ---- boundary rows (n<3 or n>=N-3): one-sided offsets gather ----
        const int* __restrict__ o = offs + (size_t)n * FD_S;
        v4f acc = (v4f){0.f, 0.f, 0.f, 0.f};
#pragma unroll
        for (int s = 0; s < FD_S; ++s) {
            const v4f v =
                *reinterpret_cast<const v4f*>(y + (size_t)(n + o[s]) * FD_B + b);
            acc += c[s] * v;
        }
        __builtin_nontemporal_store(
            acc, reinterpret_cast<v4f*>(out + (size_t)n * FD_B + b));
    }
}

extern "C" void kernel_launch(void* const* d_in, const int* in_sizes, int n_in,
                              void* d_out, int out_size, void* d_ws, size_t ws_size,
                              hipStream_t stream) {
    const float* y    = (const float*)d_in[0];
    const float* coef = (const float*)d_in[1];
    const int*   offs = (const int*)d_in[2];
    float*       out  = (float*)d_out;

    _FinDiffNonUniform_51608327029442_kernel<<<NWG, 256, 0, stream>>>(y, coef, offs, out);
}

// Round 5
// 230.869 us; speedup vs baseline: 1.1260x; 1.1260x over previous
//
#include <hip/hip_runtime.h>

// FinDiffNonUniform: out[n,b] = sum_{s<7} coef[n,s] * y[n + off[n,s], b]
// N=8192, B=4096, S=7, fp32.
//
// Round-6: LDS staging via global_load_lds. Rounds 0/2/4 proved the register
// allocator folds ANY register-resident load window to 1-2 live buffers
// (VGPR_Count 36/36/16) -> <=2 outstanding loads/wave, and R=1's 7x
// L1-amplified traffic (940 MB) saturates the L1 miss queue (effective
// latency ~2300 cy, 1.86 TB/s at 86% occupancy). global_load_lds has no
// dest VGPR: queue depth = instruction count, the compiler CANNOT serialize
// it. Each block stages its 14-row window (56 KB LDS) with 14 async
// loads/wave = 14 KB in flight per wave BY CONSTRUCTION (112 KB/CU at
// 2 blocks/CU), then reads each row ONCE from LDS (amplification 1.75x vs
// 7x, ~4x fewer L1 requests). Plain (strip,chunk) block order keeps
// concurrent addresses spread over the full 16 KB row -> all HBM channels.

#define FD_N   8192
#define FD_B   4096
#define FD_S   7
#define FD_R   8
#define HALO   3
#define WIN    (FD_R + 2 * HALO)     // 14 staged rows
#define NSTRIP (FD_N / FD_R)         // 1024
#define CHUNKF 1024                  // floats per column chunk
#define NCHUNK (FD_B / CHUNKF)       // 4
#define NWG    (NSTRIP * NCHUNK)     // 4096 blocks

typedef float v4f __attribute__((ext_vector_type(4)));
typedef unsigned int u32;

__global__ __launch_bounds__(256) void
_FinDiffNonUniform_51608327029442_kernel(const float* __restrict__ y,
                                         const float* __restrict__ coef,
                                         const int*   __restrict__ offs,
                                         float*       __restrict__ out) {
    const int strip = blockIdx.x >> 2;
    const int chunk = blockIdx.x & 3;
    const int n0    = strip * FD_R;
    const int tid   = threadIdx.x;
    const int b     = (chunk << 10) + (tid << 2);     // global column (floats)

    __shared__ float lds[WIN * CHUNKF];               // 57344 B -> 2 blocks/CU

    if (strip == 0 || strip == NSTRIP - 1) {
        // ---- edge strips: generic gather with real one-sided offsets ----
#pragma unroll
        for (int r = 0; r < FD_R; ++r) {
            const int n = n0 + r;
            const float* __restrict__ c = coef + (size_t)n * FD_S;
            const int*   __restrict__ o = offs + (size_t)n * FD_S;
            v4f acc = (v4f){0.f, 0.f, 0.f, 0.f};
#pragma unroll
            for (int s = 0; s < FD_S; ++s) {
                const v4f v = *reinterpret_cast<const v4f*>(
                    y + (size_t)(n + o[s]) * FD_B + b);
                acc += c[s] * v;
            }
            __builtin_nontemporal_store(
                acc, reinterpret_cast<v4f*>(out + (size_t)n * FD_B + b));
        }
        return;
    }

    // ---- interior: stage 14-row window into LDS, no VGPR round trip ----
    const int base = n0 - HALO;                       // first staged row
    const int wave = tid >> 6;
    const int lane = tid & 63;

    // Wave w stages byte-slice [w*1024, (w+1)*1024) of each 4 KB row.
    // LDS dest is wave-uniform base + lane*16 (hardware rule); global src is
    // per-lane. Row j -> lds[j*1024 floats], matching the linear layout.
    const char* gsrc = (const char*)y
                     + (size_t)base * (FD_B * 4)
                     + (size_t)chunk * (CHUNKF * 4)
                     + (size_t)wave * 1024
                     + (size_t)lane * 16;
    u32* lbase = reinterpret_cast<u32*>(lds) + wave * 256;   // wave slice (u32)

#pragma unroll
    for (int j = 0; j < WIN; ++j) {
        __builtin_amdgcn_global_load_lds(
            (const __attribute__((address_space(1))) u32*)(gsrc + (size_t)j * (FD_B * 4)),
            (__attribute__((address_space(3))) u32*)(lbase + j * CHUNKF),
            16, 0, 0);
    }
    __syncthreads();   // vmcnt(0) drain + barrier: whole tile resident

    // Block-uniform coefficients -> scalar loads.
    float c[FD_R][FD_S];
#pragma unroll
    for (int r = 0; r < FD_R; ++r)
#pragma unroll
        for (int s = 0; s < FD_S; ++s)
            c[r][s] = coef[(size_t)(n0 + r) * FD_S + s];

    v4f acc[FD_R];
#pragma unroll
    for (int r = 0; r < FD_R; ++r)
        acc[r] = (v4f){0.f, 0.f, 0.f, 0.f};

    // Read each staged row ONCE; row j (global row base+j) feeds acc[r]
    // with stencil index s = j - r, s in [0,7).
#pragma unroll
    for (int j = 0; j < WIN; ++j) {
        const v4f v = *reinterpret_cast<const v4f*>(&lds[j * CHUNKF + tid * 4]);
#pragma unroll
        for (int r = 0; r < FD_R; ++r) {
            const int s = j - r;
            if (s >= 0 && s < FD_S)
                acc[r] += c[r][s] * v;
        }
    }

#pragma unroll
    for (int r = 0; r < FD_R; ++r)
        __builtin_nontemporal_store(
            acc[r], reinterpret_cast<v4f*>(out + (size_t)(n0 + r) * FD_B + b));
}

extern "C" void kernel_launch(void* const* d_in, const int* in_sizes, int n_in,
                              void* d_out, int out_size, void* d_ws, size_t ws_size,
                              hipStream_t stream) {
    const float* y    = (const float*)d_in[0];
    const float* coef = (const float*)d_in[1];
    const int*   offs = (const int*)d_in[2];
    float*       out  = (float*)d_out;

    _FinDiffNonUniform_51608327029442_kernel<<<NWG, 256, 0, stream>>>(y, coef, offs, out);
}